// Round 2
// baseline (440.238 us; speedup 1.0000x reference)
//
#include <hip/hip_runtime.h>
#include <stdint.h>

#define DIMS   4096
#define NT     256
#define WAVES  (NT / 64)
#define EPL    64      // elements per lane (one wave owns a whole row)
#define F4PL   16      // float4 loads per lane
#define KSEL   16      // top-k per branch (KTOP/2)
#define CMAX   64      // candidate capacity
#define ALPHA_C 6.26f
#define PIV0   0x40133333u   // bits(2.3f): ~44 expected survivors per branch

// element index of slot i in this lane: idx = (i>>2)*256 + lane*4 + (i&3)
// inverted so smaller index -> larger key word (jax top_k tie-break: lowest index first)
#define INVIDX(i) (~((((unsigned)((i) >> 2)) << 8) + (((unsigned)lane) << 2) + ((unsigned)((i) & 3))))

#define BP(raw) (((int)(raw) > 0) ? (raw) : 0u)                       // key of relu(x)
#define BN(raw) (((int)(raw) < 0) ? ((raw) ^ 0x80000000u) : 0u)       // key of max(-x,0)

__device__ __forceinline__ float wave_fadd(float v) {
#pragma unroll
  for (int off = 1; off < 64; off <<= 1) v += __shfl_xor(v, off, 64);
  return v;
}
__device__ __forceinline__ unsigned wave_uadd(unsigned v) {
#pragma unroll
  for (int off = 1; off < 64; off <<= 1) v += __shfl_xor(v, off, 64);
  return v;
}
__device__ __forceinline__ unsigned long long shflx64(unsigned long long v, int m) {
  unsigned lo = (unsigned)v, hi = (unsigned)(v >> 32);
  lo = __shfl_xor(lo, m, 64);
  hi = __shfl_xor(hi, m, 64);
  return (((unsigned long long)hi) << 32) | lo;
}
__device__ __forceinline__ unsigned long long shflb64(unsigned long long v, int src) {
  unsigned lo = (unsigned)v, hi = (unsigned)(v >> 32);
  lo = __shfl(lo, src, 64);
  hi = __shfl(hi, src, 64);
  return (((unsigned long long)hi) << 32) | lo;
}

__global__ __launch_bounds__(NT, 4) void kcomp_kernel(const float* __restrict__ x,
                                                      float* __restrict__ out) {
  const int tid  = threadIdx.x;
  const int lane = tid & 63;
  const int wid  = tid >> 6;
  const int row  = blockIdx.x * WAVES + wid;

  __shared__ unsigned long long s_cand[WAVES][2][CMAX];
  __shared__ unsigned s_cnt[WAVES][2];

  if (lane == 0) { s_cnt[wid][0] = 0u; s_cnt[wid][1] = 0u; }  // same-wave LDS: in-order, no barrier

  const float4* xr = reinterpret_cast<const float4*>(x + (size_t)row * DIMS);

  unsigned b[EPL];
  float psum = 0.f, nsum = 0.f;
  unsigned ic0 = 0, ic1 = 0;

#pragma unroll
  for (int j = 0; j < F4PL; ++j) {
    float4 v = xr[j * 64 + lane];
    float f[4] = {v.x, v.y, v.z, v.w};
#pragma unroll
    for (int c = 0; c < 4; ++c) {
      unsigned raw = __float_as_uint(f[c]);
      b[j * 4 + c] = raw;
      unsigned bp = (f[c] > 0.f) ? raw : 0u;
      unsigned bn = (f[c] < 0.f) ? (raw ^ 0x80000000u) : 0u;
      psum += __uint_as_float(bp);
      nsum += __uint_as_float(bn);
      ic0 += (bp >= PIV0) ? 1u : 0u;
      ic1 += (bn >= PIV0) ? 1u : 0u;
    }
  }

  psum = wave_fadd(psum);
  nsum = wave_fadd(nsum);
  unsigned cc  = wave_uadd(ic0 | (ic1 << 16));
  unsigned ns0 = cc & 0xFFFFu, ns1 = cc >> 16;

  // ---- stage 1: find 32-bit key pivot with count(key >= pivot) in [KSEL, CMAX] ----
  unsigned lo[2], hi[2], nlo[2];
  bool done0 = (ns0 >= KSEL && ns0 <= CMAX);
  bool done1 = (ns1 >= KSEL && ns1 <= CMAX);
  bool st2_0 = false, st2_1 = false;
  lo[0]  = (ns0 >= KSEL) ? PIV0 : 0u;
  hi[0]  = (ns0 >= KSEL) ? 0xFFFFFFFFu : PIV0;
  nlo[0] = (ns0 >= KSEL) ? ns0 : (unsigned)DIMS;
  lo[1]  = (ns1 >= KSEL) ? PIV0 : 0u;
  hi[1]  = (ns1 >= KSEL) ? 0xFFFFFFFFu : PIV0;
  nlo[1] = (ns1 >= KSEL) ? ns1 : (unsigned)DIMS;

  for (int it = 0; it < 40 && !(done0 && done1); ++it) {
    unsigned mid0 = lo[0] + ((hi[0] - lo[0]) >> 1);
    unsigned mid1 = lo[1] + ((hi[1] - lo[1]) >> 1);
    unsigned c0 = 0, c1 = 0;
#pragma unroll
    for (int i = 0; i < EPL; ++i) {
      unsigned raw = b[i];
      c0 += (BP(raw) >= mid0) ? 1u : 0u;
      c1 += (BN(raw) >= mid1) ? 1u : 0u;
    }
    unsigned t = wave_uadd(c0 | (c1 << 16));
    unsigned t0 = t & 0xFFFFu, t1 = t >> 16;

    if (!done0) {
      if (t0 >= KSEL) { lo[0] = mid0; nlo[0] = t0; if (t0 <= CMAX) done0 = true; }
      else hi[0] = mid0;
      if (!done0) {
        if (hi[0] - lo[0] <= 1u) { done0 = true; st2_0 = (nlo[0] > CMAX); }
      }
    }
    if (!done1) {
      if (t1 >= KSEL) { lo[1] = mid1; nlo[1] = t1; if (t1 <= CMAX) done1 = true; }
      else hi[1] = mid1;
      if (!done1) {
        if (hi[1] - lo[1] <= 1u) { done1 = true; st2_1 = (nlo[1] > CMAX); }
      }
    }
  }

  unsigned long long S0 = ((unsigned long long)lo[0]) << 32;
  unsigned long long S1 = ((unsigned long long)lo[1]) << 32;

  // ---- stage 2 (rare): >CMAX exact 32-bit ties at pivot -> bisect the index word ----
  if (st2_0 | st2_1) {  // wave-uniform
#pragma unroll
    for (int br = 0; br < 2; ++br) {
      bool active = br ? st2_1 : st2_0;
      if (!active) continue;
      unsigned pivot = br ? lo[1] : lo[0];
      unsigned lo2 = 0u, hi2 = 0xFFFFFFFFu;
      unsigned nlo2 = br ? nlo[1] : nlo[0];
      for (int it = 0; it < 34 && nlo2 > CMAX; ++it) {
        unsigned mid2 = lo2 + ((hi2 - lo2) >> 1);
        unsigned c = 0;
#pragma unroll
        for (int i = 0; i < EPL; ++i) {
          unsigned raw = b[i];
          unsigned k = br ? BN(raw) : BP(raw);
          c += ((k > pivot) || (k == pivot && INVIDX(i) >= mid2)) ? 1u : 0u;
        }
        unsigned n = wave_uadd(c);
        if (n >= KSEL) { lo2 = mid2; nlo2 = n; } else hi2 = mid2;
        if (hi2 - lo2 <= 1u) break;  // 64-bit keys unique => count here <= CMAX
      }
      if (br) S1 = (((unsigned long long)pivot) << 32) | (unsigned long long)lo2;
      else    S0 = (((unsigned long long)pivot) << 32) | (unsigned long long)lo2;
    }
  }

  // ---- gather candidates (<= CMAX per branch) into this wave's LDS buffers ----
#pragma unroll
  for (int i = 0; i < EPL; ++i) {
    unsigned raw = b[i];
    unsigned bp = BP(raw);
    unsigned long long Kp = (((unsigned long long)bp) << 32) | (unsigned long long)INVIDX(i);
    if (Kp >= S0) { unsigned s = atomicAdd(&s_cnt[wid][0], 1u); if (s < CMAX) s_cand[wid][0][s] = Kp; }
    unsigned bn = BN(raw);
    unsigned long long Kn = (((unsigned long long)bn) << 32) | (unsigned long long)INVIDX(i);
    if (Kn >= S1) { unsigned s = atomicAdd(&s_cnt[wid][1], 1u); if (s < CMAX) s_cand[wid][1][s] = Kn; }
  }

  // ---- exact top-16 per branch: this wave bitonic-sorts both branches together ----
  unsigned n0 = s_cnt[wid][0]; if (n0 > CMAX) n0 = CMAX;   // same wave: LDS ops in-order
  unsigned n1 = s_cnt[wid][1]; if (n1 > CMAX) n1 = CMAX;
  unsigned long long v0 = (lane < (int)n0) ? s_cand[wid][0][lane] : 0ULL;  // real keys > 0
  unsigned long long v1 = (lane < (int)n1) ? s_cand[wid][1][lane] : 0ULL;

#pragma unroll
  for (int k = 2; k <= 64; k <<= 1) {
#pragma unroll
    for (int j = k >> 1; j > 0; j >>= 1) {
      unsigned long long o0 = shflx64(v0, j);
      unsigned long long o1 = shflx64(v1, j);
      bool asc = ((lane & k) == 0);
      bool sm  = ((lane & j) == 0);
      bool keepmin = (asc == sm);
      unsigned long long mn0 = (v0 < o0) ? v0 : o0, mx0 = (v0 < o0) ? o0 : v0;
      unsigned long long mn1 = (v1 < o1) ? v1 : o1, mx1 = (v1 < o1) ? o1 : v1;
      v0 = keepmin ? mn0 : mx0;
      v1 = keepmin ? mn1 : mx1;
    }
  }
  // ascending: top-16 in lanes 48..63; lane 48 holds the 16th-largest (threshold) key
  float tv0 = __uint_as_float((unsigned)(v0 >> 32));
  float tv1 = __uint_as_float((unsigned)(v1 >> 32));
#pragma unroll
  for (int off = 1; off < 16; off <<= 1) {
    tv0 += __shfl_xor(tv0, off, 64);
    tv1 += __shfl_xor(tv1, off, 64);
  }
  unsigned long long T0 = shflb64(v0, 48);
  unsigned long long T1 = shflb64(v1, 48);
  float a0 = ALPHA_C * (psum - __shfl(tv0, 48, 64));
  float a1 = ALPHA_C * (nsum - __shfl(tv1, 48, 64));

  // ---- emit: each lane writes back its own 64 elements (coalesced float4) ----
  float4* orow = reinterpret_cast<float4*>(out + (size_t)row * DIMS);
#pragma unroll
  for (int j = 0; j < F4PL; ++j) {
    float oc[4];
#pragma unroll
    for (int c = 0; c < 4; ++c) {
      const int i = j * 4 + c;
      unsigned raw = b[i];
      unsigned bp = BP(raw);
      unsigned bn = BN(raw);
      unsigned long long Kp = (((unsigned long long)bp) << 32) | (unsigned long long)INVIDX(i);
      unsigned long long Kn = (((unsigned long long)bn) << 32) | (unsigned long long)INVIDX(i);
      float r = 0.f;
      if (Kp >= T0) r  = __uint_as_float(bp) + a0;   // pv + p_tmp
      if (Kn >= T1) r -= __uint_as_float(bn) + a1;   // -(nv + n_tmp)
      oc[c] = r;
    }
    float4 o; o.x = oc[0]; o.y = oc[1]; o.z = oc[2]; o.w = oc[3];
    orow[j * 64 + lane] = o;
  }
}

extern "C" void kernel_launch(void* const* d_in, const int* in_sizes, int n_in,
                              void* d_out, int out_size, void* d_ws, size_t ws_size,
                              hipStream_t stream) {
  const float* x = (const float*)d_in[0];
  float* o = (float*)d_out;
  const int B = in_sizes[0] / DIMS;          // 8192 rows
  const int nblocks = B / WAVES;             // 4 rows per 256-thread block
  hipLaunchKernelGGL(kcomp_kernel, dim3(nblocks), dim3(NT), 0, stream, x, o);
}